// Round 1
// baseline (1197.328 us; speedup 1.0000x reference)
//
#include <hip/hip_runtime.h>
#include <math.h>

#define T 8
#define N 20000
#define E 320000
#define D_IN 64
#define H 128
#define EPS 1e-5f

__device__ __forceinline__ float sigm(float x) { return 1.0f / (1.0f + expf(-x)); }

// ---------------------------------------------------------------------------
// K1: degree count (edges only; self-loop added in k_dinv)
__global__ void k_deg(const int* __restrict__ edges, float* __restrict__ deg) {
    int idx = blockIdx.x * blockDim.x + threadIdx.x;
    if (idx >= T * E) return;
    int t = idx / E, e = idx - t * E;
    int dst = edges[t * 2 * E + E + e];
    atomicAdd(&deg[t * N + dst], 1.0f);
}

// K2: dinv = rsqrt(deg + 1)
__global__ void k_dinv(const float* __restrict__ deg, float* __restrict__ dinv) {
    int i = blockIdx.x * blockDim.x + threadIdx.x;
    if (i < T * N) dinv[i] = rsqrtf(deg[i] + 1.0f);
}

// K3: one wave per edge.
//   acc[dst][k] += dinv[src] * x[src][k]   (64 feature atomics, coalesced)
//   w[src]      += dinv[dst]               (1 scalar atomic, lane 0)
__global__ void k_scatter(const int* __restrict__ edges, const float* __restrict__ x,
                          const float* __restrict__ dinv, float* __restrict__ w,
                          float* __restrict__ acc) {
    int gid = (blockIdx.x * blockDim.x + threadIdx.x) >> 6;
    int lane = threadIdx.x & 63;
    if (gid >= T * E) return;
    int t = gid / E, e = gid - t * E;
    int src = edges[t * 2 * E + e];
    int dst = edges[t * 2 * E + E + e];
    float ds = dinv[t * N + src];
    if (lane == 0) {
        atomicAdd(&w[t * N + src], dinv[t * N + dst]);
    }
    atomicAdd(&acc[(t * N + dst) * 64 + lane],
              ds * x[((size_t)(t * N + src)) * 64 + lane]);
}

// K4: per-node layer-1 GEMM (64->128) with fused self-loop, final dinv scale,
// BN1 + ReLU, then alpha-weighted pooling reduction into pooled[t][128].
__global__ __launch_bounds__(256) void k_gemm_pool(
    const float* __restrict__ x, const float* __restrict__ acc,
    const float* __restrict__ dinv, const float* __restrict__ w,
    const float* __restrict__ W1, const float* __restrict__ b1,
    const float* __restrict__ g1, const float* __restrict__ be1,
    const float* __restrict__ m1, const float* __restrict__ v1,
    float* __restrict__ pooled) {
    __shared__ float Ws[64 * 128];          // [k][j]
    __shared__ float sb[128], st[128], pool[128];
    const int t = blockIdx.y;
    const int tid = threadIdx.x;
    const int n = blockIdx.x * 256 + tid;

    for (int i = tid; i < 64 * 128; i += 256) Ws[i] = W1[i];
    if (tid < 128) {
        float s = g1[tid] * rsqrtf(v1[tid] + EPS);
        sb[tid] = s;
        st[tid] = s * b1[tid] + be1[tid] - m1[tid] * s;  // folds bias + BN shift
        pool[tid] = 0.0f;
    }
    __syncthreads();

    float v[64];
    float alpha = 0.0f;
    if (n < N) {
        int node = t * N + n;
        float di = dinv[node];
        alpha = di * (w[node] + di);
        const float4* a4 = (const float4*)(acc + (size_t)node * 64);
        const float4* x4 = (const float4*)(x + (size_t)node * 64);
#pragma unroll
        for (int k4 = 0; k4 < 16; k4++) {
            float4 a = a4[k4];
            float4 xx = x4[k4];
            v[4 * k4 + 0] = di * (a.x + di * xx.x);
            v[4 * k4 + 1] = di * (a.y + di * xx.y);
            v[4 * k4 + 2] = di * (a.z + di * xx.z);
            v[4 * k4 + 3] = di * (a.w + di * xx.w);
        }
    } else {
#pragma unroll
        for (int k = 0; k < 64; k++) v[k] = 0.0f;
    }

    const int lane = tid & 63;
    for (int j4 = 0; j4 < 32; j4++) {
        float s0 = 0.f, s1 = 0.f, s2 = 0.f, s3 = 0.f;
#pragma unroll
        for (int k = 0; k < 64; k++) {
            float4 wv = *(const float4*)&Ws[k * 128 + j4 * 4];
            s0 += v[k] * wv.x;
            s1 += v[k] * wv.y;
            s2 += v[k] * wv.z;
            s3 += v[k] * wv.w;
        }
        int j = j4 * 4;
        float y0 = fmaxf(sb[j + 0] * s0 + st[j + 0], 0.f) * alpha;
        float y1 = fmaxf(sb[j + 1] * s1 + st[j + 1], 0.f) * alpha;
        float y2 = fmaxf(sb[j + 2] * s2 + st[j + 2], 0.f) * alpha;
        float y3 = fmaxf(sb[j + 3] * s3 + st[j + 3], 0.f) * alpha;
#pragma unroll
        for (int off = 32; off > 0; off >>= 1) {
            y0 += __shfl_down(y0, off);
            y1 += __shfl_down(y1, off);
            y2 += __shfl_down(y2, off);
            y3 += __shfl_down(y3, off);
        }
        if (lane == 0) {
            atomicAdd(&pool[j + 0], y0);
            atomicAdd(&pool[j + 1], y1);
            atomicAdd(&pool[j + 2], y2);
            atomicAdd(&pool[j + 3], y3);
        }
    }
    __syncthreads();
    if (tid < 128) atomicAdd(&pooled[t * 128 + tid], pool[tid]);
}

// K5: single block: emb = bn2(pooled/N @ W2 + b2), 2-layer LSTM over T=8,
// classifier. Writes d_out[0:2]=logits, d_out[2:130]=hT.
__global__ __launch_bounds__(512) void k_head(
    const float* __restrict__ pooled,
    const float* __restrict__ W2, const float* __restrict__ b2,
    const float* __restrict__ g2, const float* __restrict__ be2,
    const float* __restrict__ m2, const float* __restrict__ v2,
    const float* __restrict__ Wih0, const float* __restrict__ Whh0,
    const float* __restrict__ bih0, const float* __restrict__ bhh0,
    const float* __restrict__ Wih1, const float* __restrict__ Whh1,
    const float* __restrict__ bih1, const float* __restrict__ bhh1,
    const float* __restrict__ Wc, const float* __restrict__ bc,
    float* __restrict__ out) {
    __shared__ float pm[T][128];
    __shared__ float emb[T][128];
    __shared__ float ys[T][128];
    __shared__ float h[128], c[128], gates[512];
    const int tid = threadIdx.x;

    for (int i = tid; i < T * 128; i += 512) pm[i / 128][i & 127] = pooled[i] * (1.0f / N);
    __syncthreads();

    // emb[t][j] = bn2((pm[t] . W2[:,j]) + b2[j])
    {
        int tt = tid >> 7;       // 0..3
        int j = tid & 127;
        float s = g2[j] * rsqrtf(v2[j] + EPS);
        float sh = be2[j] - m2[j] * s;
        for (int g = 0; g < 2; g++) {
            int t = g * 4 + tt;
            float dot = 0.f;
#pragma unroll 8
            for (int k = 0; k < 128; k++) dot += pm[t][k] * W2[k * 128 + j];
            emb[t][j] = s * (dot + b2[j]) + sh;
        }
    }
    if (tid < 128) { h[tid] = 0.f; c[tid] = 0.f; }
    __syncthreads();

    // LSTM layer 0
    for (int step = 0; step < T; step++) {
        float dot = bih0[tid] + bhh0[tid];
        const float4* wi = (const float4*)(Wih0 + tid * 128);
        const float4* wh = (const float4*)(Whh0 + tid * 128);
        const float4* xt = (const float4*)emb[step];
        const float4* hh = (const float4*)h;
#pragma unroll
        for (int k4 = 0; k4 < 32; k4++) {
            float4 a = wi[k4], bx = xt[k4];
            float4 bw = wh[k4], hv = hh[k4];
            dot += a.x * bx.x + a.y * bx.y + a.z * bx.z + a.w * bx.w;
            dot += bw.x * hv.x + bw.y * hv.y + bw.z * hv.z + bw.w * hv.w;
        }
        gates[tid] = dot;
        __syncthreads();
        if (tid < 128) {
            float i_ = gates[tid], f_ = gates[128 + tid];
            float g_ = gates[256 + tid], o_ = gates[384 + tid];
            float cc = sigm(f_) * c[tid] + sigm(i_) * tanhf(g_);
            c[tid] = cc;
            float hv = sigm(o_) * tanhf(cc);
            h[tid] = hv;
            ys[step][tid] = hv;
        }
        __syncthreads();
    }

    // LSTM layer 1
    if (tid < 128) { h[tid] = 0.f; c[tid] = 0.f; }
    __syncthreads();
    for (int step = 0; step < T; step++) {
        float dot = bih1[tid] + bhh1[tid];
        const float4* wi = (const float4*)(Wih1 + tid * 128);
        const float4* wh = (const float4*)(Whh1 + tid * 128);
        const float4* xt = (const float4*)ys[step];
        const float4* hh = (const float4*)h;
#pragma unroll
        for (int k4 = 0; k4 < 32; k4++) {
            float4 a = wi[k4], bx = xt[k4];
            float4 bw = wh[k4], hv = hh[k4];
            dot += a.x * bx.x + a.y * bx.y + a.z * bx.z + a.w * bx.w;
            dot += bw.x * hv.x + bw.y * hv.y + bw.z * hv.z + bw.w * hv.w;
        }
        gates[tid] = dot;
        __syncthreads();
        if (tid < 128) {
            float i_ = gates[tid], f_ = gates[128 + tid];
            float g_ = gates[256 + tid], o_ = gates[384 + tid];
            float cc = sigm(f_) * c[tid] + sigm(i_) * tanhf(g_);
            c[tid] = cc;
            h[tid] = sigm(o_) * tanhf(cc);
        }
        __syncthreads();
    }

    if (tid < 2) {
        float dot = bc[tid];
#pragma unroll 8
        for (int k = 0; k < 128; k++) dot += h[k] * Wc[tid * 128 + k];
        out[tid] = dot;
    }
    if (tid < 128) out[2 + tid] = h[tid];
}

// ---------------------------------------------------------------------------
extern "C" void kernel_launch(void* const* d_in, const int* in_sizes, int n_in,
                              void* d_out, int out_size, void* d_ws, size_t ws_size,
                              hipStream_t stream) {
    const float* x    = (const float*)d_in[0];
    const int*   edges= (const int*)d_in[1];
    const float* W1   = (const float*)d_in[2];
    const float* b1   = (const float*)d_in[3];
    const float* g1   = (const float*)d_in[4];
    const float* be1  = (const float*)d_in[5];
    const float* m1   = (const float*)d_in[6];
    const float* v1   = (const float*)d_in[7];
    const float* W2   = (const float*)d_in[8];
    const float* b2   = (const float*)d_in[9];
    const float* g2   = (const float*)d_in[10];
    const float* be2  = (const float*)d_in[11];
    const float* m2   = (const float*)d_in[12];
    const float* v2   = (const float*)d_in[13];
    const float* Wih0 = (const float*)d_in[14];
    const float* Whh0 = (const float*)d_in[15];
    const float* bih0 = (const float*)d_in[16];
    const float* bhh0 = (const float*)d_in[17];
    const float* Wih1 = (const float*)d_in[18];
    const float* Whh1 = (const float*)d_in[19];
    const float* bih1 = (const float*)d_in[20];
    const float* bhh1 = (const float*)d_in[21];
    const float* Wc   = (const float*)d_in[22];
    const float* bc   = (const float*)d_in[23];

    float* ws = (float*)d_ws;
    float* deg    = ws;                        // T*N
    float* w      = deg + T * N;               // T*N
    float* acc    = w + T * N;                 // T*N*64
    float* pooled = acc + (size_t)T * N * 64;  // T*128
    float* dinv   = pooled + T * 128;          // T*N

    // zero deg, w, acc, pooled in one shot (dinv is fully overwritten)
    size_t zero_bytes = ((size_t)T * N * 2 + (size_t)T * N * 64 + T * 128) * sizeof(float);
    hipMemsetAsync(d_ws, 0, zero_bytes, stream);

    k_deg<<<(T * E + 255) / 256, 256, 0, stream>>>(edges, deg);
    k_dinv<<<(T * N + 255) / 256, 256, 0, stream>>>(deg, dinv);
    k_scatter<<<(T * E * 64) / 256, 256, 0, stream>>>(edges, x, dinv, w, acc);

    dim3 g4((N + 255) / 256, T);
    k_gemm_pool<<<g4, 256, 0, stream>>>(x, acc, dinv, w, W1, b1, g1, be1, m1, v1, pooled);

    k_head<<<1, 512, 0, stream>>>(pooled, W2, b2, g2, be2, m2, v2,
                                  Wih0, Whh0, bih0, bhh0, Wih1, Whh1, bih1, bhh1,
                                  Wc, bc, (float*)d_out);
}

// Round 2
// 806.491 us; speedup vs baseline: 1.4846x; 1.4846x over previous
//
#include <hip/hip_runtime.h>
#include <math.h>

#define T 8
#define N 20000
#define E 320000
#define D_IN 64
#define H 128
#define EPS 1e-5f

__device__ __forceinline__ float sigm(float x) { return 1.0f / (1.0f + expf(-x)); }

// ---------------------------------------------------------------------------
// K1: integer degree count per (t, dst)
__global__ void k_deg(const int* __restrict__ edges, int* __restrict__ deg) {
    int idx = blockIdx.x * blockDim.x + threadIdx.x;
    if (idx >= T * E) return;
    int t = idx / E, e = idx - t * E;
    int dst = edges[t * 2 * E + E + e];
    atomicAdd(&deg[t * N + dst], 1);
}

// K2: per-t exclusive scan of deg -> offs (global position t*E + prefix),
// copy to cursor, and dinv = rsqrt(deg+1). One 1024-thread block per t;
// each thread owns 20 consecutive elements (N = 1000*20).
__global__ __launch_bounds__(1024) void k_scan(
    const int* __restrict__ deg, int* __restrict__ offs, int* __restrict__ cursor,
    float* __restrict__ dinv) {
    const int t = blockIdx.x;
    const int tid = threadIdx.x;
    __shared__ int tot[1024];
    const int base = t * N;
    int local[20];
    int sum = 0;
    if (tid < 1000) {
        const int* dp = deg + base + tid * 20;
#pragma unroll
        for (int i = 0; i < 20; i++) { local[i] = dp[i]; sum += local[i]; }
    }
    tot[tid] = sum;
    __syncthreads();
    for (int off = 1; off < 1024; off <<= 1) {
        int v = (tid >= off) ? tot[tid - off] : 0;
        __syncthreads();
        tot[tid] += v;
        __syncthreads();
    }
    if (tid < 1000) {
        int run = t * E + tot[tid] - sum;  // exclusive prefix, global slot
        int* op = offs + base + tid * 20;
        int* cp = cursor + base + tid * 20;
        float* dv = dinv + base + tid * 20;
#pragma unroll
        for (int i = 0; i < 20; i++) {
            op[i] = run; cp[i] = run; run += local[i];
            dv[i] = rsqrtf((float)local[i] + 1.0f);
        }
    }
}

// K3: CSR fill (1 scalar atomic per edge) + w[src] += dinv[dst]
__global__ void k_fill(const int* __restrict__ edges, const float* __restrict__ dinv,
                       int* __restrict__ cursor, float* __restrict__ w,
                       int* __restrict__ eidx) {
    int idx = blockIdx.x * blockDim.x + threadIdx.x;
    if (idx >= T * E) return;
    int t = idx / E, e = idx - t * E;
    int src = edges[t * 2 * E + e];
    int dst = edges[t * 2 * E + E + e];
    int pos = atomicAdd(&cursor[t * N + dst], 1);
    eidx[pos] = src;
    atomicAdd(&w[t * N + src], dinv[t * N + dst]);
}

// K4: gather — one wave per node, lane = feature. No atomics.
__global__ __launch_bounds__(256) void k_gather(
    const int* __restrict__ eidx, const int* __restrict__ offs,
    const int* __restrict__ deg, const float* __restrict__ dinv,
    const float* __restrict__ x, float* __restrict__ agg) {
    int node = (blockIdx.x * 256 + threadIdx.x) >> 6;
    int lane = threadIdx.x & 63;
    if (node >= T * N) return;
    int t = node / N;
    int start = offs[node];
    int cnt = deg[node];
    const float* xt = x + (size_t)t * N * 64;
    const float* dv = dinv + t * N;
    float acc = 0.f;
    int e = 0;
    for (; e + 3 < cnt; e += 4) {
        int s0 = eidx[start + e + 0], s1 = eidx[start + e + 1];
        int s2 = eidx[start + e + 2], s3 = eidx[start + e + 3];
        float c0 = dv[s0], c1 = dv[s1], c2 = dv[s2], c3 = dv[s3];
        float x0 = xt[s0 * 64 + lane], x1 = xt[s1 * 64 + lane];
        float x2 = xt[s2 * 64 + lane], x3 = xt[s3 * 64 + lane];
        acc += c0 * x0 + c1 * x1 + c2 * x2 + c3 * x3;
    }
    for (; e < cnt; e++) {
        int s0 = eidx[start + e];
        acc += dv[s0] * xt[s0 * 64 + lane];
    }
    agg[(size_t)node * 64 + lane] = acc;
}

// K5: per-node layer-1 GEMM (64->128) with fused self-loop, final dinv scale,
// BN1 + ReLU, then alpha-weighted pooling reduction into pooled[t][128].
__global__ __launch_bounds__(256) void k_gemm_pool(
    const float* __restrict__ x, const float* __restrict__ agg,
    const float* __restrict__ dinv, const float* __restrict__ w,
    const float* __restrict__ W1, const float* __restrict__ b1,
    const float* __restrict__ g1, const float* __restrict__ be1,
    const float* __restrict__ m1, const float* __restrict__ v1,
    float* __restrict__ pooled) {
    __shared__ float Ws[64 * 128];          // [k][j]
    __shared__ float sb[128], st[128], pool[128];
    const int t = blockIdx.y;
    const int tid = threadIdx.x;
    const int n = blockIdx.x * 256 + tid;

    for (int i = tid; i < 64 * 128; i += 256) Ws[i] = W1[i];
    if (tid < 128) {
        float s = g1[tid] * rsqrtf(v1[tid] + EPS);
        sb[tid] = s;
        st[tid] = s * b1[tid] + be1[tid] - m1[tid] * s;  // folds bias + BN shift
        pool[tid] = 0.0f;
    }
    __syncthreads();

    float v[64];
    float alpha = 0.0f;
    if (n < N) {
        int node = t * N + n;
        float di = dinv[node];
        alpha = di * (w[node] + di);
        const float4* a4 = (const float4*)(agg + (size_t)node * 64);
        const float4* x4 = (const float4*)(x + (size_t)node * 64);
#pragma unroll
        for (int k4 = 0; k4 < 16; k4++) {
            float4 a = a4[k4];
            float4 xx = x4[k4];
            v[4 * k4 + 0] = di * (a.x + di * xx.x);
            v[4 * k4 + 1] = di * (a.y + di * xx.y);
            v[4 * k4 + 2] = di * (a.z + di * xx.z);
            v[4 * k4 + 3] = di * (a.w + di * xx.w);
        }
    } else {
#pragma unroll
        for (int k = 0; k < 64; k++) v[k] = 0.0f;
    }

    const int lane = tid & 63;
    for (int j4 = 0; j4 < 32; j4++) {
        float s0 = 0.f, s1 = 0.f, s2 = 0.f, s3 = 0.f;
#pragma unroll
        for (int k = 0; k < 64; k++) {
            float4 wv = *(const float4*)&Ws[k * 128 + j4 * 4];
            s0 += v[k] * wv.x;
            s1 += v[k] * wv.y;
            s2 += v[k] * wv.z;
            s3 += v[k] * wv.w;
        }
        int j = j4 * 4;
        float y0 = fmaxf(sb[j + 0] * s0 + st[j + 0], 0.f) * alpha;
        float y1 = fmaxf(sb[j + 1] * s1 + st[j + 1], 0.f) * alpha;
        float y2 = fmaxf(sb[j + 2] * s2 + st[j + 2], 0.f) * alpha;
        float y3 = fmaxf(sb[j + 3] * s3 + st[j + 3], 0.f) * alpha;
#pragma unroll
        for (int off = 32; off > 0; off >>= 1) {
            y0 += __shfl_down(y0, off);
            y1 += __shfl_down(y1, off);
            y2 += __shfl_down(y2, off);
            y3 += __shfl_down(y3, off);
        }
        if (lane == 0) {
            atomicAdd(&pool[j + 0], y0);
            atomicAdd(&pool[j + 1], y1);
            atomicAdd(&pool[j + 2], y2);
            atomicAdd(&pool[j + 3], y3);
        }
    }
    __syncthreads();
    if (tid < 128) atomicAdd(&pooled[t * 128 + tid], pool[tid]);
}

// K6: single block: emb = bn2(pooled/N @ W2 + b2), 2-layer LSTM over T=8,
// classifier. Writes d_out[0:2]=logits, d_out[2:130]=hT.
__global__ __launch_bounds__(512) void k_head(
    const float* __restrict__ pooled,
    const float* __restrict__ W2, const float* __restrict__ b2,
    const float* __restrict__ g2, const float* __restrict__ be2,
    const float* __restrict__ m2, const float* __restrict__ v2,
    const float* __restrict__ Wih0, const float* __restrict__ Whh0,
    const float* __restrict__ bih0, const float* __restrict__ bhh0,
    const float* __restrict__ Wih1, const float* __restrict__ Whh1,
    const float* __restrict__ bih1, const float* __restrict__ bhh1,
    const float* __restrict__ Wc, const float* __restrict__ bc,
    float* __restrict__ out) {
    __shared__ float pm[T][128];
    __shared__ float emb[T][128];
    __shared__ float ys[T][128];
    __shared__ float h[128], c[128], gates[512];
    const int tid = threadIdx.x;

    for (int i = tid; i < T * 128; i += 512) pm[i / 128][i & 127] = pooled[i] * (1.0f / N);
    __syncthreads();

    {
        int tt = tid >> 7;
        int j = tid & 127;
        float s = g2[j] * rsqrtf(v2[j] + EPS);
        float sh = be2[j] - m2[j] * s;
        for (int g = 0; g < 2; g++) {
            int t = g * 4 + tt;
            float dot = 0.f;
#pragma unroll 8
            for (int k = 0; k < 128; k++) dot += pm[t][k] * W2[k * 128 + j];
            emb[t][j] = s * (dot + b2[j]) + sh;
        }
    }
    if (tid < 128) { h[tid] = 0.f; c[tid] = 0.f; }
    __syncthreads();

    for (int step = 0; step < T; step++) {
        float dot = bih0[tid] + bhh0[tid];
        const float4* wi = (const float4*)(Wih0 + tid * 128);
        const float4* wh = (const float4*)(Whh0 + tid * 128);
        const float4* xt = (const float4*)emb[step];
        const float4* hh = (const float4*)h;
#pragma unroll
        for (int k4 = 0; k4 < 32; k4++) {
            float4 a = wi[k4], bx = xt[k4];
            float4 bw = wh[k4], hv = hh[k4];
            dot += a.x * bx.x + a.y * bx.y + a.z * bx.z + a.w * bx.w;
            dot += bw.x * hv.x + bw.y * hv.y + bw.z * hv.z + bw.w * hv.w;
        }
        gates[tid] = dot;
        __syncthreads();
        if (tid < 128) {
            float i_ = gates[tid], f_ = gates[128 + tid];
            float g_ = gates[256 + tid], o_ = gates[384 + tid];
            float cc = sigm(f_) * c[tid] + sigm(i_) * tanhf(g_);
            c[tid] = cc;
            float hv = sigm(o_) * tanhf(cc);
            h[tid] = hv;
            ys[step][tid] = hv;
        }
        __syncthreads();
    }

    if (tid < 128) { h[tid] = 0.f; c[tid] = 0.f; }
    __syncthreads();
    for (int step = 0; step < T; step++) {
        float dot = bih1[tid] + bhh1[tid];
        const float4* wi = (const float4*)(Wih1 + tid * 128);
        const float4* wh = (const float4*)(Whh1 + tid * 128);
        const float4* xt = (const float4*)ys[step];
        const float4* hh = (const float4*)h;
#pragma unroll
        for (int k4 = 0; k4 < 32; k4++) {
            float4 a = wi[k4], bx = xt[k4];
            float4 bw = wh[k4], hv = hh[k4];
            dot += a.x * bx.x + a.y * bx.y + a.z * bx.z + a.w * bx.w;
            dot += bw.x * hv.x + bw.y * hv.y + bw.z * hv.z + bw.w * hv.w;
        }
        gates[tid] = dot;
        __syncthreads();
        if (tid < 128) {
            float i_ = gates[tid], f_ = gates[128 + tid];
            float g_ = gates[256 + tid], o_ = gates[384 + tid];
            float cc = sigm(f_) * c[tid] + sigm(i_) * tanhf(g_);
            c[tid] = cc;
            h[tid] = sigm(o_) * tanhf(cc);
        }
        __syncthreads();
    }

    if (tid < 2) {
        float dot = bc[tid];
#pragma unroll 8
        for (int k = 0; k < 128; k++) dot += h[k] * Wc[tid * 128 + k];
        out[tid] = dot;
    }
    if (tid < 128) out[2 + tid] = h[tid];
}

// ---------------------------------------------------------------------------
extern "C" void kernel_launch(void* const* d_in, const int* in_sizes, int n_in,
                              void* d_out, int out_size, void* d_ws, size_t ws_size,
                              hipStream_t stream) {
    const float* x    = (const float*)d_in[0];
    const int*   edges= (const int*)d_in[1];
    const float* W1   = (const float*)d_in[2];
    const float* b1   = (const float*)d_in[3];
    const float* g1   = (const float*)d_in[4];
    const float* be1  = (const float*)d_in[5];
    const float* m1   = (const float*)d_in[6];
    const float* v1   = (const float*)d_in[7];
    const float* W2   = (const float*)d_in[8];
    const float* b2   = (const float*)d_in[9];
    const float* g2   = (const float*)d_in[10];
    const float* be2  = (const float*)d_in[11];
    const float* m2   = (const float*)d_in[12];
    const float* v2   = (const float*)d_in[13];
    const float* Wih0 = (const float*)d_in[14];
    const float* Whh0 = (const float*)d_in[15];
    const float* bih0 = (const float*)d_in[16];
    const float* bhh0 = (const float*)d_in[17];
    const float* Wih1 = (const float*)d_in[18];
    const float* Whh1 = (const float*)d_in[19];
    const float* bih1 = (const float*)d_in[20];
    const float* bhh1 = (const float*)d_in[21];
    const float* Wc   = (const float*)d_in[22];
    const float* bc   = (const float*)d_in[23];

    char* ws = (char*)d_ws;
    // zeroed region first: deg (int T*N), w (float T*N), pooled (float T*128)
    int*   deg    = (int*)ws;                                  ws += (size_t)T * N * 4;
    float* w      = (float*)ws;                                ws += (size_t)T * N * 4;
    float* pooled = (float*)ws;                                ws += (size_t)T * 128 * 4;
    size_t zero_bytes = (size_t)((char*)ws - (char*)d_ws);
    int*   offs   = (int*)ws;                                  ws += (size_t)T * N * 4;
    int*   cursor = (int*)ws;                                  ws += (size_t)T * N * 4;
    float* dinv   = (float*)ws;                                ws += (size_t)T * N * 4;
    int*   eidx   = (int*)ws;                                  ws += (size_t)T * E * 4;
    float* agg    = (float*)ws;

    hipMemsetAsync(d_ws, 0, zero_bytes, stream);

    k_deg<<<(T * E + 255) / 256, 256, 0, stream>>>(edges, deg);
    k_scan<<<T, 1024, 0, stream>>>(deg, offs, cursor, dinv);
    k_fill<<<(T * E + 255) / 256, 256, 0, stream>>>(edges, dinv, cursor, w, eidx);
    k_gather<<<(T * N * 64) / 256, 256, 0, stream>>>(eidx, offs, deg, dinv, x, agg);

    dim3 g4((N + 255) / 256, T);
    k_gemm_pool<<<g4, 256, 0, stream>>>(x, agg, dinv, w, W1, b1, g1, be1, m1, v1, pooled);

    k_head<<<1, 512, 0, stream>>>(pooled, W2, b2, g2, be2, m2, v2,
                                  Wih0, Whh0, bih0, bhh0, Wih1, Whh1, bih1, bhh1,
                                  Wc, bc, (float*)d_out);
}